// Round 10
// baseline (328.407 us; speedup 1.0000x reference)
//
#include <hip/hip_runtime.h>

#define M_DIM 8192
#define N_DIM 4096
#define K_DIM 4096

typedef __bf16 bf16x8 __attribute__((ext_vector_type(8)));
typedef float f32x16 __attribute__((ext_vector_type(16)));

// bf16 round-to-nearest-even from fp32 (no NaN in this problem)
__device__ __forceinline__ unsigned short f2bf(float f) {
    unsigned u = __float_as_uint(f);
    u += 0x7FFFu + ((u >> 16) & 1u);
    return (unsigned short)(u >> 16);
}

// Bit-exact replica of reference _cast_e4m3 (round-half-even, subnormals, sat 448)
__device__ __forceinline__ float cast_e4m3(float v) {
    float a = fminf(fabsf(v), 448.0f);
    float am = fmaxf(a, 0x1p-9f);
    int e = (int)((__float_as_uint(am) >> 23) & 0xFFu) - 127;   // floor(log2(am)), exact
    e = (e < -6) ? -6 : e;
    float step = __uint_as_float((unsigned)(e - 3 + 127) << 23); // 2^(e-3)
    float q = rintf(a / step) * step;                            // a/step exact, RNE tie
    q = fminf(q, 448.0f);
    return (v < 0.0f) ? -q : q;
}

// x: per-row 1x128 blocks. One 32-lane group per block, 4 floats/lane.
__global__ __launch_bounds__(256) void quant_x(const float* __restrict__ X,
                                               unsigned short* __restrict__ Xq) {
    const int g = threadIdx.x >> 5;
    const int l = threadIdx.x & 31;
    const long rb = (long)blockIdx.x * 8 + g;
    const int row = (int)(rb >> 5);
    const int kb = (int)(rb & 31);
    const size_t base = (size_t)row * K_DIM + kb * 128 + l * 4;
    const float4 v = *(const float4*)&X[base];
    float amax = fmaxf(fmaxf(fabsf(v.x), fabsf(v.y)), fmaxf(fabsf(v.z), fabsf(v.w)));
    #pragma unroll
    for (int m = 16; m >= 1; m >>= 1)
        amax = fmaxf(amax, __shfl_xor(amax, m));
    const float scale = fmaxf(amax, 1e-12f) / 448.0f;
    ushort4 o;
    o.x = f2bf(cast_e4m3(v.x / scale) * scale);
    o.y = f2bf(cast_e4m3(v.y / scale) * scale);
    o.z = f2bf(cast_e4m3(v.z / scale) * scale);
    o.w = f2bf(cast_e4m3(v.w / scale) * scale);
    *(ushort4*)&Xq[base] = o;
}

// w: 128x128 tiles. One 256-thread block per tile; values held in registers.
__global__ __launch_bounds__(256) void quant_w(const float* __restrict__ W,
                                               unsigned short* __restrict__ Wq) {
    const int tile = blockIdx.x;
    const int tr = tile >> 5;
    const int tc = tile & 31;
    const int t = threadIdx.x;
    const int c4 = (t & 31) * 4;
    const float* base = W + (size_t)(tr * 128) * K_DIM + tc * 128;

    float4 v[16];
    float amax = 0.0f;
    #pragma unroll
    for (int p = 0; p < 16; ++p) {
        const int r = p * 8 + (t >> 5);
        v[p] = *(const float4*)&base[(size_t)r * K_DIM + c4];
        amax = fmaxf(amax, fmaxf(fmaxf(fabsf(v[p].x), fabsf(v[p].y)),
                                 fmaxf(fabsf(v[p].z), fabsf(v[p].w))));
    }
    #pragma unroll
    for (int m = 32; m >= 1; m >>= 1)
        amax = fmaxf(amax, __shfl_xor(amax, m));
    __shared__ float red[4];
    if ((t & 63) == 0) red[t >> 6] = amax;
    __syncthreads();
    const float am4 = fmaxf(fmaxf(red[0], red[1]), fmaxf(red[2], red[3]));
    const float scale = fmaxf(am4, 1e-12f) / 448.0f;

    unsigned short* out = Wq + (size_t)(tr * 128) * K_DIM + tc * 128;
    #pragma unroll
    for (int p = 0; p < 16; ++p) {
        const int r = p * 8 + (t >> 5);
        ushort4 o;
        o.x = f2bf(cast_e4m3(v[p].x / scale) * scale);
        o.y = f2bf(cast_e4m3(v[p].y / scale) * scale);
        o.z = f2bf(cast_e4m3(v[p].z / scale) * scale);
        o.w = f2bf(cast_e4m3(v[p].w / scale) * scale);
        *(ushort4*)&out[(size_t)r * K_DIM + c4] = o;
    }
}

#define GLOAD16(g, l)                                                          \
    __builtin_amdgcn_global_load_lds(                                          \
        (const __attribute__((address_space(1))) void*)(g),                    \
        (__attribute__((address_space(3))) void*)(l), 16, 0, 0)

// ========== 256x256 8-phase GEMM, BK=64, 8 waves, MFMA 32x32x16 ==========
// R5's exact proven structure (LDS layout, stage ledger, vmcnt(4), swizzle,
// LGKM8) with the compute swapped to v_mfma_f32_32x32x16_bf16 (2495 vs 2075
// TF ubench: per-phase MFMA-pipe floor 620 -> 516 cyc, half the issue slots).
// LDS element bases: A buf0: 0, A buf1: 16384, B buf0: 32768, B buf1: 49152.
// Ledger: P1:A0(u+1) P2:A1(u+1) P3:B0(u+2) P4:B1(u+2)+vmcnt(4)
//         P5:A0(u+2) P6:A1(u+2) P7:B0(u+3) P8:B1(u+3)+vmcnt(4)  [R5-proven]
// Loop runs all 64 tiles with kt clamped to 63 (R6/R9-proven dead-tail trick).
// Fragments (32x32x16): A row=lane&31, k=(lane>>5)*8+j; B col=lane&31, same k;
// C/D col=lane&31, row=(reg&3)+8*(reg>>2)+4*(lane>>5)  [m74/m101 verified].
// Wave tile 128x64 = 4 row-frags x 2 col-frags; phase (mh,nh) = 2 frags x
// 4 k-steps = 8 MFMA, k-chains interleaved across fr to break acc dependency.
// Swizzle: identical to R5 (row bits 0-2 = lane bits 0-2; col granule
// k*2+(lane>>5) is 8-granule aligned) -> conflict-free proof carries over.

#define BARRIER() __builtin_amdgcn_s_barrier()
#define LGKM0() asm volatile("s_waitcnt lgkmcnt(0)" ::: "memory")
#define LGKM8() asm volatile("s_waitcnt lgkmcnt(8)" ::: "memory")
#define VM4()   asm volatile("s_waitcnt vmcnt(4)" ::: "memory")
#define VM0()   asm volatile("s_waitcnt vmcnt(0)" ::: "memory")
#define PRIO1() __builtin_amdgcn_s_setprio(1)
#define PRIO0() __builtin_amdgcn_s_setprio(0)

#define STAGE(G, grow0, kt, ebase, ht) do {                                    \
    const int _kt = (kt) > 63 ? 63 : (kt);                                     \
    const unsigned short* _s0 = (G) +                                          \
        (size_t)((grow0) + (ht) * 128 + w * 8 + sr) * K_DIM + _kt * 64 + src_col; \
    const unsigned short* _s1 = _s0 + (size_t)64 * K_DIM;                      \
    char* _lb = (char*)lds + (ebase) * 2 + ((ht) * 128 + w * 8) * 128;         \
    GLOAD16(_s0, _lb);                                                         \
    GLOAD16(_s1, _lb + 8192);                                                  \
} while (0)

// A frags for one 64-row half (mh): a[fr2][k], rows mh*64+fr2*32+(lane&31)
#define LDA32(mh) do {                                                         \
    _Pragma("unroll") for (int _f = 0; _f < 2; ++_f) {                         \
        const int _row = wm * 128 + (mh) * 64 + _f * 32 + l31;                 \
        _Pragma("unroll") for (int _k = 0; _k < 4; ++_k)                       \
            a[_f][_k] = *(const bf16x8*)&lds[abase + _row * 64 +               \
                                             ((_k * 16 + hk32) ^ rsw)];        \
    }                                                                          \
} while (0)

// B frags for one 32-col block (nh): dst[k], row wn*64+nh*32+(lane&31)
#define LDB32(nh, dst) do {                                                    \
    const int _row = wn * 64 + (nh) * 32 + l31;                                \
    _Pragma("unroll") for (int _k = 0; _k < 4; ++_k)                           \
        dst[_k] = *(const bf16x8*)&lds[bbase + _row * 64 +                     \
                                       ((_k * 16 + hk32) ^ rsw)];              \
} while (0)

// 8 MFMA: frags (mh*2+fr2, nh), k-chains interleaved across fr2
#define MMA32(mh, nh, bb) do {                                                 \
    _Pragma("unroll") for (int _k = 0; _k < 4; ++_k)                           \
    _Pragma("unroll") for (int _f = 0; _f < 2; ++_f)                           \
        acc[(mh) * 2 + _f][nh] = __builtin_amdgcn_mfma_f32_32x32x16_bf16(      \
            a[_f][_k], bb[_k], acc[(mh) * 2 + _f][nh], 0, 0, 0);               \
} while (0)

__global__ __launch_bounds__(512, 2) void gemm256(const unsigned short* __restrict__ A,
                                                  const unsigned short* __restrict__ B,
                                                  const float* __restrict__ bias,
                                                  float* __restrict__ C) {
    __shared__ __align__(16) unsigned short lds[65536];   // 128 KiB

    const int t = threadIdx.x;
    const int lane = t & 63;
    const int w = t >> 6;                 // 0..7
    const int wm = w >> 2, wn = w & 3;    // 2M x 4N wave grid

    int bid = blockIdx.x;
    bid = (bid & 7) * 64 + (bid >> 3);    // 512 blocks, %8==0 -> bijective
    const int bm = bid >> 4, bn = bid & 15;
    const size_t brow = (size_t)bm * 256, bcol = (size_t)bn * 256;

    // stage-side (R5-identical): row-in-8 = lane>>3; inverse-swizzled source col
    const int sr = lane >> 3;
    const int src_col = (((lane & 7) ^ ((lane >> 3) & 7)) << 3);
    // read-side
    const int l31 = lane & 31;
    const int hk32 = (lane >> 5) * 8;     // k-offset within 16-k frag
    const int rsw = (lane & 7) << 3;      // col ^= (row&7)<<3 (row&7 == lane&7)

    f32x16 acc[4][2] = {};
    bf16x8 a[2][4], b0[4], b1[4];
    int abase, bbase;

    // prologue: tile0 (A+B) -> buf0, tile1 B-halves -> buf1 (R5-identical)
    STAGE(A, brow, 0, 0, 0);     STAGE(A, brow, 0, 0, 1);
    STAGE(B, bcol, 0, 32768, 0); STAGE(B, bcol, 0, 32768, 1);
    STAGE(B, bcol, 1, 49152, 0); STAGE(B, bcol, 1, 49152, 1);
    VM4(); BARRIER();

    for (int u = 0; u < 64; u += 2) {
        // P1: quads (0,0) of tile u
        abase = 0; bbase = 32768;
        LDA32(0); LDB32(0, b0);
        STAGE(A, brow, u + 1, 16384, 0);
        LGKM8();
        BARRIER(); LGKM0();
        PRIO1(); MMA32(0, 0, b0); PRIO0();
        BARRIER();
        // P2: (0,1)
        LDB32(1, b1);
        STAGE(A, brow, u + 1, 16384, 1);
        BARRIER(); LGKM0();
        PRIO1(); MMA32(0, 1, b1); PRIO0();
        BARRIER();
        // P3: (1,1)
        LDA32(1);
        STAGE(B, bcol, u + 2, 32768, 0);
        BARRIER(); LGKM0();
        PRIO1(); MMA32(1, 1, b1); PRIO0();
        BARRIER();
        // P4: (1,0), K-tile boundary
        STAGE(B, bcol, u + 2, 32768, 1);
        BARRIER();
        PRIO1(); MMA32(1, 0, b0); PRIO0();
        VM4();
        BARRIER();
        // P5: tile u+1 (buf1)
        abase = 16384; bbase = 49152;
        LDA32(0); LDB32(0, b0);
        STAGE(A, brow, u + 2, 0, 0);
        LGKM8();
        BARRIER(); LGKM0();
        PRIO1(); MMA32(0, 0, b0); PRIO0();
        BARRIER();
        // P6
        LDB32(1, b1);
        STAGE(A, brow, u + 2, 0, 1);
        BARRIER(); LGKM0();
        PRIO1(); MMA32(0, 1, b1); PRIO0();
        BARRIER();
        // P7
        LDA32(1);
        STAGE(B, bcol, u + 3, 49152, 0);
        BARRIER(); LGKM0();
        PRIO1(); MMA32(1, 1, b1); PRIO0();
        BARRIER();
        // P8
        STAGE(B, bcol, u + 3, 49152, 1);
        BARRIER();
        PRIO1(); MMA32(1, 0, b0); PRIO0();
        VM4();
        BARRIER();
    }

    VM0();   // drain dead tail stages

    // C write: frag (fr, fc): row = wm*128 + fr*32 + (reg&3)+8*(reg>>2)+4*(lane>>5)
    //                          col = wn*64 + fc*32 + (lane&31)
    const int hi4 = (lane >> 5) * 4;
    #pragma unroll
    for (int fr = 0; fr < 4; ++fr) {
        #pragma unroll
        for (int fc = 0; fc < 2; ++fc) {
            const size_t col = bcol + wn * 64 + fc * 32 + l31;
            const float bv = bias[col];
            #pragma unroll
            for (int reg = 0; reg < 16; ++reg) {
                const size_t row = brow + wm * 128 + fr * 32 +
                                   (reg & 3) + 8 * (reg >> 2) + hi4;
                C[row * (size_t)N_DIM + col] = acc[fr][fc][reg] + bv;
            }
        }
    }
}

extern "C" void kernel_launch(void* const* d_in, const int* in_sizes, int n_in,
                              void* d_out, int out_size, void* d_ws, size_t ws_size,
                              hipStream_t stream) {
    const float* x = (const float*)d_in[0];
    const float* w = (const float*)d_in[1];
    const float* bias = (const float*)d_in[2];
    float* out = (float*)d_out;

    unsigned short* xq = (unsigned short*)d_ws;
    unsigned short* wq = xq + (size_t)M_DIM * K_DIM;

    quant_x<<<(M_DIM * (K_DIM / 128)) / 8, 256, 0, stream>>>(x, xq);
    quant_w<<<(N_DIM / 128) * (K_DIM / 128), 256, 0, stream>>>(w, wq);
    gemm256<<<(M_DIM / 256) * (N_DIM / 256), 512, 0, stream>>>(xq, wq, bias, out);
}

// Round 11
// 294.312 us; speedup vs baseline: 1.1158x; 1.1158x over previous
//
#include <hip/hip_runtime.h>

#define M_DIM 8192
#define N_DIM 4096
#define K_DIM 4096

typedef __bf16 bf16x8 __attribute__((ext_vector_type(8)));
typedef float f32x4 __attribute__((ext_vector_type(4)));

// bf16 round-to-nearest-even from fp32 (no NaN in this problem)
__device__ __forceinline__ unsigned short f2bf(float f) {
    unsigned u = __float_as_uint(f);
    u += 0x7FFFu + ((u >> 16) & 1u);
    return (unsigned short)(u >> 16);
}

// Bit-exact replica of reference _cast_e4m3 (round-half-even, subnormals, sat 448)
__device__ __forceinline__ float cast_e4m3(float v) {
    float a = fminf(fabsf(v), 448.0f);
    float am = fmaxf(a, 0x1p-9f);
    int e = (int)((__float_as_uint(am) >> 23) & 0xFFu) - 127;   // floor(log2(am)), exact
    e = (e < -6) ? -6 : e;
    float step = __uint_as_float((unsigned)(e - 3 + 127) << 23); // 2^(e-3)
    float q = rintf(a / step) * step;                            // a/step exact, RNE tie
    q = fminf(q, 448.0f);
    return (v < 0.0f) ? -q : q;
}

// x: per-row 1x128 blocks. One 32-lane group per block, 4 floats/lane.
__global__ __launch_bounds__(256) void quant_x(const float* __restrict__ X,
                                               unsigned short* __restrict__ Xq) {
    const int g = threadIdx.x >> 5;
    const int l = threadIdx.x & 31;
    const long rb = (long)blockIdx.x * 8 + g;
    const int row = (int)(rb >> 5);
    const int kb = (int)(rb & 31);
    const size_t base = (size_t)row * K_DIM + kb * 128 + l * 4;
    const float4 v = *(const float4*)&X[base];
    float amax = fmaxf(fmaxf(fabsf(v.x), fabsf(v.y)), fmaxf(fabsf(v.z), fabsf(v.w)));
    #pragma unroll
    for (int m = 16; m >= 1; m >>= 1)
        amax = fmaxf(amax, __shfl_xor(amax, m));
    const float scale = fmaxf(amax, 1e-12f) / 448.0f;
    ushort4 o;
    o.x = f2bf(cast_e4m3(v.x / scale) * scale);
    o.y = f2bf(cast_e4m3(v.y / scale) * scale);
    o.z = f2bf(cast_e4m3(v.z / scale) * scale);
    o.w = f2bf(cast_e4m3(v.w / scale) * scale);
    *(ushort4*)&Xq[base] = o;
}

// w: 128x128 tiles. One 256-thread block per tile; values held in registers.
__global__ __launch_bounds__(256) void quant_w(const float* __restrict__ W,
                                               unsigned short* __restrict__ Wq) {
    const int tile = blockIdx.x;
    const int tr = tile >> 5;
    const int tc = tile & 31;
    const int t = threadIdx.x;
    const int c4 = (t & 31) * 4;
    const float* base = W + (size_t)(tr * 128) * K_DIM + tc * 128;

    float4 v[16];
    float amax = 0.0f;
    #pragma unroll
    for (int p = 0; p < 16; ++p) {
        const int r = p * 8 + (t >> 5);
        v[p] = *(const float4*)&base[(size_t)r * K_DIM + c4];
        amax = fmaxf(amax, fmaxf(fmaxf(fabsf(v[p].x), fabsf(v[p].y)),
                                 fmaxf(fabsf(v[p].z), fabsf(v[p].w))));
    }
    #pragma unroll
    for (int m = 32; m >= 1; m >>= 1)
        amax = fmaxf(amax, __shfl_xor(amax, m));
    __shared__ float red[4];
    if ((t & 63) == 0) red[t >> 6] = amax;
    __syncthreads();
    const float am4 = fmaxf(fmaxf(red[0], red[1]), fmaxf(red[2], red[3]));
    const float scale = fmaxf(am4, 1e-12f) / 448.0f;

    unsigned short* out = Wq + (size_t)(tr * 128) * K_DIM + tc * 128;
    #pragma unroll
    for (int p = 0; p < 16; ++p) {
        const int r = p * 8 + (t >> 5);
        ushort4 o;
        o.x = f2bf(cast_e4m3(v[p].x / scale) * scale);
        o.y = f2bf(cast_e4m3(v[p].y / scale) * scale);
        o.z = f2bf(cast_e4m3(v[p].z / scale) * scale);
        o.w = f2bf(cast_e4m3(v[p].w / scale) * scale);
        *(ushort4*)&out[(size_t)r * K_DIM + c4] = o;
    }
}

#define GLOAD16(g, l)                                                          \
    __builtin_amdgcn_global_load_lds(                                          \
        (const __attribute__((address_space(1))) void*)(g),                    \
        (__attribute__((address_space(3))) void*)(l), 16, 0, 0)

// ======= 256x256 GEMM, BK=64, 8 waves, MERGED 4-phase (R5 ledger halved) =====
// Identical LDS layout / swizzle / lane patterns to R5 (conflict-free proven:
// SQ_LDS_BANK_CONFLICT==0). Phases merged 8->4 per 2-tile iteration: each
// phase = 2 C-quadrants = 32 MFMA; barrier pairs halve, amortizing the fixed
// sync cost (~530cy/phase measured as the 49% MfmaUtil gap) over 2x MFMA.
// LDS element bases: A buf0: 0, A buf1: 16384, B buf0: 32768, B buf1: 49152.
// Per tile u:  PA: reads {a0(8), b0(4), b1(4)}; stages A(u+1) (4 loads, other-
//                  parity A-buf; its tile-(u-1) reads drained at PB(u-1) lgkm,
//                  >=1 trailing barrier earlier); barrier; lgkm0;
//                  MMA(0,0)+MMA(0,1); barrier.
//              PB: reads {a1(8)}; stages B(u+2) (4 loads, same-parity B-buf;
//                  tile-u B reads drained at PA(u) lgkm); barrier; lgkm0;
//                  MMA(1,1)+MMA(1,0); vmcnt(4); barrier.
// vmcnt(4) at PB(u): outstanding oldest->newest = B(u+1)[PB(u-1)], A(u+1)
// [PA(u)], B(u+2)[PB(u)] = 12 loads; drains 8 = B(u+1)+A(u+1) (issued >=1
// merged phase ~2300cy earlier > 900cy HBM), leaves B(u+2). PA(u+1) reads
// A(u+1), B(u+1): both drained. Stage-over-read separation: every stage is
// >=1 trailing barrier after its target's reads drained (barrier semantics:
// post-trailing-barrier code runs after ALL waves' lgkm0 — R5's proof).
// kt clamped to 63: tail stages write dead regions (R6/R9-proven). Loop runs
// all 64 tiles, no tapered epilogue.

#define BARRIER() __builtin_amdgcn_s_barrier()
#define LGKM0() asm volatile("s_waitcnt lgkmcnt(0)" ::: "memory")
#define VM4()   asm volatile("s_waitcnt vmcnt(4)" ::: "memory")
#define VM0()   asm volatile("s_waitcnt vmcnt(0)" ::: "memory")
#define PRIO1() __builtin_amdgcn_s_setprio(1)
#define PRIO0() __builtin_amdgcn_s_setprio(0)

#define STAGE(G, grow0, kt, ebase, ht) do {                                    \
    const int _kt = (kt) > 63 ? 63 : (kt);                                     \
    const unsigned short* _s0 = (G) +                                          \
        (size_t)((grow0) + (ht) * 128 + w * 8 + sr) * K_DIM + _kt * 64 + src_col; \
    const unsigned short* _s1 = _s0 + (size_t)64 * K_DIM;                      \
    char* _lb = (char*)lds + (ebase) * 2 + ((ht) * 128 + w * 8) * 128;         \
    GLOAD16(_s0, _lb);                                                         \
    GLOAD16(_s1, _lb + 8192);                                                  \
} while (0)

#define LDA(mh, ebase) do {                                                    \
    _Pragma("unroll") for (int _m = 0; _m < 4; ++_m) {                         \
        const int _row = wm * 128 + (mh) * 64 + _m * 16 + lr;                  \
        a[_m][0] = *(const bf16x8*)&lds[(ebase) + _row * 64 + ((0  + hk) ^ rsw)]; \
        a[_m][1] = *(const bf16x8*)&lds[(ebase) + _row * 64 + ((32 + hk) ^ rsw)]; \
    }                                                                          \
} while (0)

#define LDB(nh, dst, ebase) do {                                               \
    _Pragma("unroll") for (int _n = 0; _n < 2; ++_n) {                         \
        const int _row = wn * 64 + (nh) * 32 + _n * 16 + lr;                   \
        dst[_n][0] = *(const bf16x8*)&lds[(ebase) + _row * 64 + ((0  + hk) ^ rsw)]; \
        dst[_n][1] = *(const bf16x8*)&lds[(ebase) + _row * 64 + ((32 + hk) ^ rsw)]; \
    }                                                                          \
} while (0)

#define MMA(mh, nh, bb) do {                                                   \
    _Pragma("unroll") for (int _m = 0; _m < 4; ++_m)                           \
    _Pragma("unroll") for (int _n = 0; _n < 2; ++_n)                           \
    _Pragma("unroll") for (int _k = 0; _k < 2; ++_k)                           \
        acc[(mh) * 4 + _m][(nh) * 2 + _n] =                                    \
            __builtin_amdgcn_mfma_f32_16x16x32_bf16(                           \
                a[_m][_k], bb[_n][_k], acc[(mh) * 4 + _m][(nh) * 2 + _n], 0, 0, 0); \
} while (0)

__global__ __launch_bounds__(512, 2) void gemm256(const unsigned short* __restrict__ A,
                                                  const unsigned short* __restrict__ B,
                                                  const float* __restrict__ bias,
                                                  float* __restrict__ C) {
    __shared__ __align__(16) unsigned short lds[65536];   // 128 KiB

    const int t = threadIdx.x;
    const int lane = t & 63;
    const int w = t >> 6;                 // 0..7
    const int wm = w >> 2, wn = w & 3;    // 2M x 4N wave grid

    int bid = blockIdx.x;
    bid = (bid & 7) * 64 + (bid >> 3);    // 512 blocks, %8==0 -> bijective
    const int bm = bid >> 4, bn = bid & 15;
    const size_t brow = (size_t)bm * 256, bcol = (size_t)bn * 256;

    // stage-side (R5-identical): row-in-8 = lane>>3; inverse-swizzled source col
    const int sr = lane >> 3;
    const int src_col = (((lane & 7) ^ ((lane >> 3) & 7)) << 3);
    // read-side (R5-identical)
    const int lr = lane & 15;
    const int hk = (lane >> 4) * 8;
    const int rsw = (lane & 7) << 3;      // col ^= (row&7)<<3, row&7 == lane&7

    f32x4 acc[8][4] = {};
    bf16x8 a[4][2], b0[2][2], b1[2][2];

    // prologue: A(0),B(0) -> even bufs, B(1) -> odd B-buf (12 loads);
    // vmcnt(4) drains tile0, leaves B(1) in flight (= steady PA entry state).
    STAGE(A, brow, 0, 0, 0);     STAGE(A, brow, 0, 0, 1);
    STAGE(B, bcol, 0, 32768, 0); STAGE(B, bcol, 0, 32768, 1);
    STAGE(B, bcol, 1, 49152, 0); STAGE(B, bcol, 1, 49152, 1);
    VM4(); BARRIER();

    for (int u = 0; u < 64; u += 2) {
        // ---- tile u (even bufs) ----
        // PA: quads (0,0)+(0,1)
        LDA(0, 0); LDB(0, b0, 32768); LDB(1, b1, 32768);
        STAGE(A, brow, u + 1, 16384, 0); STAGE(A, brow, u + 1, 16384, 1);
        BARRIER(); LGKM0();
        PRIO1(); MMA(0, 0, b0); MMA(0, 1, b1); PRIO0();
        BARRIER();
        // PB: quads (1,1)+(1,0)
        LDA(1, 0);
        STAGE(B, bcol, u + 2, 32768, 0); STAGE(B, bcol, u + 2, 32768, 1);
        BARRIER(); LGKM0();
        PRIO1(); MMA(1, 1, b1); MMA(1, 0, b0); PRIO0();
        VM4();
        BARRIER();

        // ---- tile u+1 (odd bufs) ----
        // PA
        LDA(0, 16384); LDB(0, b0, 49152); LDB(1, b1, 49152);
        STAGE(A, brow, u + 2, 0, 0); STAGE(A, brow, u + 2, 0, 1);
        BARRIER(); LGKM0();
        PRIO1(); MMA(0, 0, b0); MMA(0, 1, b1); PRIO0();
        BARRIER();
        // PB
        LDA(1, 16384);
        STAGE(B, bcol, u + 3, 49152, 0); STAGE(B, bcol, u + 3, 49152, 1);
        BARRIER(); LGKM0();
        PRIO1(); MMA(1, 1, b1); MMA(1, 0, b0); PRIO0();
        VM4();
        BARRIER();
    }

    VM0();   // drain dead tail stages before endpgm

    // C write: acc[i][j] -> row = wm*128 + i*16 + (lane>>4)*4 + jj, col = wn*64 + j*16 + (lane&15)
    #pragma unroll
    for (int i = 0; i < 8; ++i) {
        const size_t row_base = brow + wm * 128 + i * 16 + (lane >> 4) * 4;
        #pragma unroll
        for (int j = 0; j < 4; ++j) {
            const size_t col = bcol + wn * 64 + j * 16 + lr;
            const float bv = bias[col];
            #pragma unroll
            for (int jj = 0; jj < 4; ++jj)
                C[(row_base + jj) * (size_t)N_DIM + col] = acc[i][j][jj] + bv;
        }
    }
}

extern "C" void kernel_launch(void* const* d_in, const int* in_sizes, int n_in,
                              void* d_out, int out_size, void* d_ws, size_t ws_size,
                              hipStream_t stream) {
    const float* x = (const float*)d_in[0];
    const float* w = (const float*)d_in[1];
    const float* bias = (const float*)d_in[2];
    float* out = (float*)d_out;

    unsigned short* xq = (unsigned short*)d_ws;
    unsigned short* wq = xq + (size_t)M_DIM * K_DIM;

    quant_x<<<(M_DIM * (K_DIM / 128)) / 8, 256, 0, stream>>>(x, xq);
    quant_w<<<(N_DIM / 128) * (K_DIM / 128), 256, 0, stream>>>(w, wq);
    gemm256<<<(M_DIM / 256) * (N_DIM / 256), 512, 0, stream>>>(xq, wq, bias, out);
}

// Round 12
// 292.944 us; speedup vs baseline: 1.1211x; 1.0047x over previous
//
#include <hip/hip_runtime.h>

#define M_DIM 8192
#define N_DIM 4096
#define K_DIM 4096

typedef __bf16 bf16x8 __attribute__((ext_vector_type(8)));
typedef float f32x4 __attribute__((ext_vector_type(4)));

// bf16 round-to-nearest-even from fp32 (no NaN in this problem)
__device__ __forceinline__ unsigned short f2bf(float f) {
    unsigned u = __float_as_uint(f);
    u += 0x7FFFu + ((u >> 16) & 1u);
    return (unsigned short)(u >> 16);
}

// Bit-exact replica of reference _cast_e4m3 (round-half-even, subnormals, sat 448)
__device__ __forceinline__ float cast_e4m3(float v) {
    float a = fminf(fabsf(v), 448.0f);
    float am = fmaxf(a, 0x1p-9f);
    int e = (int)((__float_as_uint(am) >> 23) & 0xFFu) - 127;   // floor(log2(am)), exact
    e = (e < -6) ? -6 : e;
    float step = __uint_as_float((unsigned)(e - 3 + 127) << 23); // 2^(e-3)
    float q = rintf(a / step) * step;                            // a/step exact, RNE tie
    q = fminf(q, 448.0f);
    return (v < 0.0f) ? -q : q;
}

// x: per-row 1x128 blocks. One 32-lane group per block, 4 floats/lane.
__global__ __launch_bounds__(256) void quant_x(const float* __restrict__ X,
                                               unsigned short* __restrict__ Xq) {
    const int g = threadIdx.x >> 5;
    const int l = threadIdx.x & 31;
    const long rb = (long)blockIdx.x * 8 + g;
    const int row = (int)(rb >> 5);
    const int kb = (int)(rb & 31);
    const size_t base = (size_t)row * K_DIM + kb * 128 + l * 4;
    const float4 v = *(const float4*)&X[base];
    float amax = fmaxf(fmaxf(fabsf(v.x), fabsf(v.y)), fmaxf(fabsf(v.z), fabsf(v.w)));
    #pragma unroll
    for (int m = 16; m >= 1; m >>= 1)
        amax = fmaxf(amax, __shfl_xor(amax, m));
    const float scale = fmaxf(amax, 1e-12f) / 448.0f;
    ushort4 o;
    o.x = f2bf(cast_e4m3(v.x / scale) * scale);
    o.y = f2bf(cast_e4m3(v.y / scale) * scale);
    o.z = f2bf(cast_e4m3(v.z / scale) * scale);
    o.w = f2bf(cast_e4m3(v.w / scale) * scale);
    *(ushort4*)&Xq[base] = o;
}

// w: 128x128 tiles. One 256-thread block per tile; values held in registers.
__global__ __launch_bounds__(256) void quant_w(const float* __restrict__ W,
                                               unsigned short* __restrict__ Wq) {
    const int tile = blockIdx.x;
    const int tr = tile >> 5;
    const int tc = tile & 31;
    const int t = threadIdx.x;
    const int c4 = (t & 31) * 4;
    const float* base = W + (size_t)(tr * 128) * K_DIM + tc * 128;

    float4 v[16];
    float amax = 0.0f;
    #pragma unroll
    for (int p = 0; p < 16; ++p) {
        const int r = p * 8 + (t >> 5);
        v[p] = *(const float4*)&base[(size_t)r * K_DIM + c4];
        amax = fmaxf(amax, fmaxf(fmaxf(fabsf(v[p].x), fabsf(v[p].y)),
                                 fmaxf(fabsf(v[p].z), fabsf(v[p].w))));
    }
    #pragma unroll
    for (int m = 32; m >= 1; m >>= 1)
        amax = fmaxf(amax, __shfl_xor(amax, m));
    __shared__ float red[4];
    if ((t & 63) == 0) red[t >> 6] = amax;
    __syncthreads();
    const float am4 = fmaxf(fmaxf(red[0], red[1]), fmaxf(red[2], red[3]));
    const float scale = fmaxf(am4, 1e-12f) / 448.0f;

    unsigned short* out = Wq + (size_t)(tr * 128) * K_DIM + tc * 128;
    #pragma unroll
    for (int p = 0; p < 16; ++p) {
        const int r = p * 8 + (t >> 5);
        ushort4 o;
        o.x = f2bf(cast_e4m3(v[p].x / scale) * scale);
        o.y = f2bf(cast_e4m3(v[p].y / scale) * scale);
        o.z = f2bf(cast_e4m3(v[p].z / scale) * scale);
        o.w = f2bf(cast_e4m3(v[p].w / scale) * scale);
        *(ushort4*)&out[(size_t)r * K_DIM + c4] = o;
    }
}

#define GLOAD16(g, l)                                                          \
    __builtin_amdgcn_global_load_lds(                                          \
        (const __attribute__((address_space(1))) void*)(g),                    \
        (__attribute__((address_space(3))) void*)(l), 16, 0, 0)

// == 256x256 GEMM, BK=64, 8 waves, merged 4-phase, COMPILER-COUNTED lgkm ==
// R11's exact LDS layout / swizzle / stage ledger / vmcnt(4) (proven: 0 bank
// conflicts, deterministic). Change vs R11: the blanket leading LGKM0 per
// phase is REMOVED — it serialized the full phase read-drain (up to 128KB
// block-wide ~1000cy on the shared LDS pipe) before any MFMA. Instead reads
// are issued k0-group-first and MFMAs ordered k0-before-k1: codegen's
// mandatory dataflow waitcnt then emits minimal counted lgkmcnt(N) before
// each MFMA cluster (m97-style), exposing only the first ~6 reads and hiding
// the rest under MFMA. Correctness is compiler-guaranteed (no instruction
// consumes an unloaded register). A trailing LGKM0 before each trailing
// barrier (free — all reads consumed by the MFMAs) preserves the cross-wave
// stage-over-read proof verbatim: buffer reads drain before the trailing
// barrier; the overwriting stage is >=1 phase later.
// Ledger per tile u (unchanged): PA reads {a0,b0,b1}, stages A(u+1) both
// halves; PB reads {a1}, stages B(u+2) both halves, vmcnt(4) (drains
// B(u+1)+A(u+1), issued >=1 merged phase ~2300cy earlier > 900cy HBM;
// leaves B(u+2)). kt clamped to 63: tail stages write dead regions.

#define BARRIER() __builtin_amdgcn_s_barrier()
#define LGKM0() asm volatile("s_waitcnt lgkmcnt(0)" ::: "memory")
#define VM4()   asm volatile("s_waitcnt vmcnt(4)" ::: "memory")
#define VM0()   asm volatile("s_waitcnt vmcnt(0)" ::: "memory")
#define PRIO1() __builtin_amdgcn_s_setprio(1)
#define PRIO0() __builtin_amdgcn_s_setprio(0)

#define STAGE(G, grow0, kt, ebase, ht) do {                                    \
    const int _kt = (kt) > 63 ? 63 : (kt);                                     \
    const unsigned short* _s0 = (G) +                                          \
        (size_t)((grow0) + (ht) * 128 + w * 8 + sr) * K_DIM + _kt * 64 + src_col; \
    const unsigned short* _s1 = _s0 + (size_t)64 * K_DIM;                      \
    char* _lb = (char*)lds + (ebase) * 2 + ((ht) * 128 + w * 8) * 128;         \
    GLOAD16(_s0, _lb);                                                         \
    GLOAD16(_s1, _lb + 8192);                                                  \
} while (0)

// k-half fragment loads (kk = 0/1 selects k elements [0,32)/[32,64))
#define LDAK(mh, ebase, kk) do {                                               \
    _Pragma("unroll") for (int _m = 0; _m < 4; ++_m) {                         \
        const int _row = wm * 128 + (mh) * 64 + _m * 16 + lr;                  \
        a[_m][kk] = *(const bf16x8*)&lds[(ebase) + _row * 64 +                 \
                                         (((kk) * 32 + hk) ^ rsw)];            \
    }                                                                          \
} while (0)

#define LDBK(nh, dst, ebase, kk) do {                                          \
    _Pragma("unroll") for (int _n = 0; _n < 2; ++_n) {                         \
        const int _row = wn * 64 + (nh) * 32 + _n * 16 + lr;                   \
        dst[_n][kk] = *(const bf16x8*)&lds[(ebase) + _row * 64 +               \
                                           (((kk) * 32 + hk) ^ rsw)];          \
    }                                                                          \
} while (0)

// one k-slice of a quadrant: 8 MFMA
#define MMAK(mh, nh, bb, kk) do {                                              \
    _Pragma("unroll") for (int _m = 0; _m < 4; ++_m)                           \
    _Pragma("unroll") for (int _n = 0; _n < 2; ++_n)                           \
        acc[(mh) * 4 + _m][(nh) * 2 + _n] =                                    \
            __builtin_amdgcn_mfma_f32_16x16x32_bf16(                           \
                a[_m][kk], bb[_n][kk], acc[(mh) * 4 + _m][(nh) * 2 + _n],      \
                0, 0, 0);                                                      \
} while (0)

__global__ __launch_bounds__(512, 2) void gemm256(const unsigned short* __restrict__ A,
                                                  const unsigned short* __restrict__ B,
                                                  const float* __restrict__ bias,
                                                  float* __restrict__ C) {
    __shared__ __align__(16) unsigned short lds[65536];   // 128 KiB

    const int t = threadIdx.x;
    const int lane = t & 63;
    const int w = t >> 6;                 // 0..7
    const int wm = w >> 2, wn = w & 3;    // 2M x 4N wave grid

    int bid = blockIdx.x;
    bid = (bid & 7) * 64 + (bid >> 3);    // 512 blocks, %8==0 -> bijective
    const int bm = bid >> 4, bn = bid & 15;
    const size_t brow = (size_t)bm * 256, bcol = (size_t)bn * 256;

    // stage-side (R5-identical): row-in-8 = lane>>3; inverse-swizzled source col
    const int sr = lane >> 3;
    const int src_col = (((lane & 7) ^ ((lane >> 3) & 7)) << 3);
    // read-side (R5-identical)
    const int lr = lane & 15;
    const int hk = (lane >> 4) * 8;
    const int rsw = (lane & 7) << 3;      // col ^= (row&7)<<3, row&7 == lane&7

    f32x4 acc[8][4] = {};
    bf16x8 a[4][2], b0[2][2], b1[2][2];

    // prologue: A(0),B(0) -> even bufs, B(1) -> odd B-buf (12 loads);
    // vmcnt(4) drains tile0, leaves B(1) in flight (= steady PA entry state).
    STAGE(A, brow, 0, 0, 0);     STAGE(A, brow, 0, 0, 1);
    STAGE(B, bcol, 0, 32768, 0); STAGE(B, bcol, 0, 32768, 1);
    STAGE(B, bcol, 1, 49152, 0); STAGE(B, bcol, 1, 49152, 1);
    VM4(); BARRIER();

    for (int u = 0; u < 64; u += 2) {
        // ---- tile u (even bufs) ----
        // PA: Q(0,0)+Q(0,1); reads issued k0-group-first for counted auto-waits
        LDAK(0, 0, 0); LDBK(0, b0, 32768, 0);          // group1: 6 reads (k0)
        LDAK(0, 0, 1); LDBK(0, b0, 32768, 1);          // group2: 6 (k1)
        LDBK(1, b1, 32768, 0); LDBK(1, b1, 32768, 1);  // group3: 4 (b1)
        STAGE(A, brow, u + 1, 16384, 0); STAGE(A, brow, u + 1, 16384, 1);
        BARRIER();
        PRIO1();
        MMAK(0, 0, b0, 0);                 // auto-wait drains group1 only
        MMAK(0, 0, b0, 1);                 // group2 drained under k0 MFMA
        MMAK(0, 1, b1, 0); MMAK(0, 1, b1, 1);
        PRIO0();
        LGKM0();                           // free: all reads consumed
        BARRIER();
        // PB: Q(1,1)+Q(1,0)
        LDAK(1, 0, 0); LDAK(1, 0, 1);
        STAGE(B, bcol, u + 2, 32768, 0); STAGE(B, bcol, u + 2, 32768, 1);
        BARRIER();
        PRIO1();
        MMAK(1, 1, b1, 0); MMAK(1, 0, b0, 0);   // need a1 k0 only
        MMAK(1, 1, b1, 1); MMAK(1, 0, b0, 1);
        PRIO0();
        VM4();
        LGKM0();
        BARRIER();

        // ---- tile u+1 (odd bufs) ----
        // PA
        LDAK(0, 16384, 0); LDBK(0, b0, 49152, 0);
        LDAK(0, 16384, 1); LDBK(0, b0, 49152, 1);
        LDBK(1, b1, 49152, 0); LDBK(1, b1, 49152, 1);
        STAGE(A, brow, u + 2, 0, 0); STAGE(A, brow, u + 2, 0, 1);
        BARRIER();
        PRIO1();
        MMAK(0, 0, b0, 0);
        MMAK(0, 0, b0, 1);
        MMAK(0, 1, b1, 0); MMAK(0, 1, b1, 1);
        PRIO0();
        LGKM0();
        BARRIER();
        // PB
        LDAK(1, 16384, 0); LDAK(1, 16384, 1);
        STAGE(B, bcol, u + 3, 49152, 0); STAGE(B, bcol, u + 3, 49152, 1);
        BARRIER();
        PRIO1();
        MMAK(1, 1, b1, 0); MMAK(1, 0, b0, 0);
        MMAK(1, 1, b1, 1); MMAK(1, 0, b0, 1);
        PRIO0();
        VM4();
        LGKM0();
        BARRIER();
    }

    VM0();   // drain dead tail stages before endpgm

    // C write: acc[i][j] -> row = wm*128 + i*16 + (lane>>4)*4 + jj, col = wn*64 + j*16 + (lane&15)
    #pragma unroll
    for (int i = 0; i < 8; ++i) {
        const size_t row_base = brow + wm * 128 + i * 16 + (lane >> 4) * 4;
        #pragma unroll
        for (int j = 0; j < 4; ++j) {
            const size_t col = bcol + wn * 64 + j * 16 + lr;
            const float bv = bias[col];
            #pragma unroll
            for (int jj = 0; jj < 4; ++jj)
                C[(row_base + jj) * (size_t)N_DIM + col] = acc[i][j][jj] + bv;
        }
    }
}

extern "C" void kernel_launch(void* const* d_in, const int* in_sizes, int n_in,
                              void* d_out, int out_size, void* d_ws, size_t ws_size,
                              hipStream_t stream) {
    const float* x = (const float*)d_in[0];
    const float* w = (const float*)d_in[1];
    const float* bias = (const float*)d_in[2];
    float* out = (float*)d_out;

    unsigned short* xq = (unsigned short*)d_ws;
    unsigned short* wq = xq + (size_t)M_DIM * K_DIM;

    quant_x<<<(M_DIM * (K_DIM / 128)) / 8, 256, 0, stream>>>(x, xq);
    quant_w<<<(N_DIM / 128) * (K_DIM / 128), 256, 0, stream>>>(w, wq);
    gemm256<<<(M_DIM / 256) * (N_DIM / 256), 512, 0, stream>>>(xq, wq, bias, out);
}